// Round 8
// baseline (203.161 us; speedup 1.0000x reference)
//
#include <hip/hip_runtime.h>
#include <cstdint>

#define DIM 768
#define SEQ 2048
#define NB 2
#define NH 16
#define HD 48
#define NROWS (NB*SEQ)   // 4096

typedef __attribute__((ext_vector_type(8))) short bf16x8;
typedef __attribute__((ext_vector_type(4))) float f32x4;
typedef __attribute__((ext_vector_type(16))) float f32x16;
typedef unsigned int u32;

__device__ __forceinline__ short f2bf(float f) {
    union { float f; uint32_t u; } v; v.f = f;
    uint32_t u = v.u;
    uint32_t r = (u + 0x7FFFu + ((u >> 16) & 1u)) >> 16;
    return (short)r;
}

// RNE pack of two f32 -> one dword of 2 bf16 (lo = first arg)
__device__ __forceinline__ u32 cvtpk(float lo, float hi) {
    u32 r;
    asm("v_cvt_pk_bf16_f32 %0, %1, %2" : "=v"(r) : "v"(lo), "v"(hi));
    return r;
}
__device__ __forceinline__ bf16x8 pack8(float4 a, float4 b) {
    int4 w = make_int4((int)cvtpk(a.x, a.y), (int)cvtpk(a.z, a.w),
                       (int)cvtpk(b.x, b.y), (int)cvtpk(b.z, b.w));
    return __builtin_bit_cast(bf16x8, w);
}

#define MAX3(a,b,c) fmaxf(fmaxf((a),(b)),(c))

// ---------------------------------------------------------------------------
// bf16 MFMA GEMM, fused fp32->bf16 staging (UNCHANGED R7 control — will
// surface in top-5 counters once flash drops below it).
// ---------------------------------------------------------------------------
template<bool A_F32, bool OUT_F32>
__global__ __launch_bounds__(256)
void gemm96(const void* __restrict__ Av,
            const float* __restrict__ B0, const float* __restrict__ B1,
            const float* __restrict__ B2,
            void* __restrict__ C0v, void* __restrict__ C1v, void* __restrict__ C2v)
{
    const float* B = B0; void* Cv = C0v;
    if (blockIdx.z == 1) { B = B1; Cv = C1v; }
    else if (blockIdx.z == 2) { B = B2; Cv = C2v; }

    __shared__ short As[128*64];
    __shared__ short Bs[96*64];

    const int tid  = threadIdx.x;
    const int lane = tid & 63;
    const int wid  = tid >> 6;
    const int wr = wid >> 1, wc = wid & 1;
    const int m  = lane & 15, kb = lane >> 4;
    const int m0 = blockIdx.y * 128, n0 = blockIdx.x * 96;

    f32x4 acc[4][3];
#pragma unroll
    for (int i = 0; i < 4; ++i)
#pragma unroll
        for (int j = 0; j < 3; ++j) acc[i][j] = (f32x4){0.f,0.f,0.f,0.f};

    bf16x8 sa[4], sb[3];

#define LOAD_A(k0, i) {                                                       \
        int c = tid + (i)*256; int row = c >> 3, gs = (c & 7) ^ (row & 7);    \
        if (A_F32) {                                                          \
            const float* p = (const float*)Av + (size_t)(m0+row)*DIM + (k0) + gs*8; \
            sa[i] = pack8(*(const float4*)p, *(const float4*)(p+4));          \
        } else {                                                              \
            sa[i] = *(const bf16x8*)((const short*)Av + (size_t)(m0+row)*DIM + (k0) + gs*8); \
        } }
#define LOAD_B(k0, i) {                                                       \
        int c = tid + (i)*256; int row = c >> 3, gs = (c & 7) ^ (row & 7);    \
        const float* p = B + (size_t)(n0+row)*DIM + (k0) + gs*8;              \
        sb[i] = pack8(*(const float4*)p, *(const float4*)(p+4)); }

#pragma unroll
    for (int i = 0; i < 4; ++i) LOAD_A(0, i);
#pragma unroll
    for (int i = 0; i < 3; ++i) LOAD_B(0, i);

    for (int kt = 0; kt < DIM/64; ++kt) {
        __syncthreads();
#pragma unroll
        for (int i = 0; i < 4; ++i) {
            int c = tid + i*256;
            *(bf16x8*)&As[(c>>3)*64 + (c&7)*8] = sa[i];
        }
#pragma unroll
        for (int i = 0; i < 3; ++i) {
            int c = tid + i*256;
            *(bf16x8*)&Bs[(c>>3)*64 + (c&7)*8] = sb[i];
        }
        __syncthreads();

        if (kt < DIM/64 - 1) {
            int k0 = (kt+1)*64;
#pragma unroll
            for (int i = 0; i < 4; ++i) LOAD_A(k0, i);
#pragma unroll
            for (int i = 0; i < 3; ++i) LOAD_B(k0, i);
        }

        bf16x8 af[2][4], bfr[2][3];
#pragma unroll
        for (int t = 0; t < 2; ++t) {
            int sl = ((t*4 + kb) ^ (m & 7)) * 8;
#pragma unroll
            for (int f = 0; f < 4; ++f)
                af[t][f]  = *(const bf16x8*)&As[(wr*64 + f*16 + m)*64 + sl];
#pragma unroll
            for (int f = 0; f < 3; ++f)
                bfr[t][f] = *(const bf16x8*)&Bs[(wc*48 + f*16 + m)*64 + sl];
        }
#pragma unroll
        for (int fm = 0; fm < 4; ++fm)
#pragma unroll
            for (int fn = 0; fn < 3; ++fn) {
                acc[fm][fn] = __builtin_amdgcn_mfma_f32_16x16x32_bf16(af[0][fm], bfr[0][fn], acc[fm][fn], 0, 0, 0);
                acc[fm][fn] = __builtin_amdgcn_mfma_f32_16x16x32_bf16(af[1][fm], bfr[1][fn], acc[fm][fn], 0, 0, 0);
            }
    }
#undef LOAD_A
#undef LOAD_B

#pragma unroll
    for (int fm = 0; fm < 4; ++fm)
#pragma unroll
        for (int fn = 0; fn < 3; ++fn) {
            int col = n0 + wc*48 + fn*16 + m;
#pragma unroll
            for (int r = 0; r < 4; ++r) {
                int row = m0 + wr*64 + fm*16 + kb*4 + r;
                if (OUT_F32)
                    ((float*)Cv)[(size_t)row*DIM + col] = acc[fm][fn][r];
                else
                    ((short*)Cv)[(size_t)row*DIM + col] = f2bf(acc[fm][fn][r]);
            }
        }
}

// ---------------------------------------------------------------------------
// Flash attention v3: R6/R7-verified math/layout, restructured for occupancy.
//  - 128-thread blocks (2 waves), q-tile 64 -> grid 1024 = 4 blocks/CU
//    (was 512 = 2/CU, grid-limited at OccupancyPercent 18.6).
//  - double-buffered K/V LDS, ONE barrier per KV tile: top-of-iter barrier
//    proves all waves finished iter t-1, so storing buf[(t+1)&1]
//    (= buf[(t-1)&1]) cannot race prior readers.
//  - max3-shaped row-max reduction (32 fmax -> 16 max3-fusable).
// ---------------------------------------------------------------------------
__global__ __launch_bounds__(128)
void flash3(const short* __restrict__ Qb, const short* __restrict__ Kb,
            const short* __restrict__ Vb, short* __restrict__ Ctx)
{
    __shared__ short K_lds[2][64*64];
    __shared__ short Vt_lds[2][64*68];

    const int tid  = threadIdx.x;
    const int wid  = tid >> 6, lane = tid & 63;
    const int r    = lane & 31, hi = lane >> 5;
    const size_t base = (size_t)blockIdx.z*SEQ*DIM + (size_t)blockIdx.y*HD;
    const int q0 = blockIdx.x*64 + wid*32;
    const float C2  = 0.20823688f;   // 48^-0.5 * log2(e)
    const float THR = 11.5f;         // defer-max threshold (~8 nats)

    // zero V^T pad rows d=48..63 in BOTH buffers (read by PV A-frags)
    for (int i = tid; i < 2*16*68; i += 128) {
        int bb = i / (16*68), rr = i - bb*(16*68);
        Vt_lds[bb][48*68 + rr] = 0;
    }

    bf16x8 qf[3];
#pragma unroll
    for (int s = 0; s < 3; ++s)
        qf[s] = *(const bf16x8*)&Qb[base + (size_t)(q0 + r)*DIM + s*16 + hi*8];

    f32x16 z16;
#pragma unroll
    for (int i = 0; i < 16; ++i) z16[i] = 0.f;

    f32x16 acc0 = z16, acc1 = z16;
    float m_i = -1e30f, l_i = 0.f;

    // K staging: 512 chunks (64 rows x 8 slots of 8 bf16), 4/thread.
    // Physical slot ps holds logical slot ps^(row&7) (pre-swizzled source).
    int krow[4], kps[4];
#pragma unroll
    for (int i = 0; i < 4; ++i) {
        int c = tid + i*128;
        krow[i] = c >> 3; kps[i] = c & 7;
    }
    // V staging: thread covers row=tid&63, d = (tid>>6)*24 .. +23 (3 x bf16x8)
    const int vrow = tid & 63, vd0 = (tid >> 6) * 24;

    bf16x8 kreg[4], vreg[3];
#pragma unroll
    for (int i = 0; i < 4; ++i) {
        int ls = kps[i] ^ (krow[i] & 7);
        kreg[i] = *(const bf16x8*)&Kb[base + (size_t)krow[i]*DIM + ls*8];
    }
#pragma unroll
    for (int j = 0; j < 3; ++j)
        vreg[j] = *(const bf16x8*)&Vb[base + (size_t)vrow*DIM + vd0 + j*8];

    // prologue store -> buffer 0
#pragma unroll
    for (int i = 0; i < 4; ++i)
        *(bf16x8*)&K_lds[0][krow[i]*64 + kps[i]*8] = kreg[i];
#pragma unroll
    for (int j = 0; j < 3; ++j)
#pragma unroll
        for (int e = 0; e < 8; ++e)
            Vt_lds[0][(vd0 + j*8 + e)*68 + vrow] = vreg[j][e];

    for (int t = 0; t < SEQ/64; ++t) {
        const int cur = t & 1;
        __syncthreads();   // buf[cur] ready; all waves past iter t-1

        if (t + 1 < SEQ/64) {          // issue next-tile global loads (T14)
            int c0 = (t+1)*64;
#pragma unroll
            for (int i = 0; i < 4; ++i) {
                int ls = kps[i] ^ (krow[i] & 7);
                kreg[i] = *(const bf16x8*)&Kb[base + (size_t)(c0 + krow[i])*DIM + ls*8];
            }
#pragma unroll
            for (int j = 0; j < 3; ++j)
                vreg[j] = *(const bf16x8*)&Vb[base + (size_t)(c0 + vrow)*DIM + vd0 + j*8];
        }

        // S^T = K * Q^T
        f32x16 sa[2];
#pragma unroll
        for (int ct = 0; ct < 2; ++ct) {
            f32x16 a = z16;
#pragma unroll
            for (int s = 0; s < 3; ++s) {
                int row = ct*32 + r;
                bf16x8 kf = *(const bf16x8*)&K_lds[cur][row*64 + ((s*2+hi) ^ (row&7))*8];
                a = __builtin_amdgcn_mfma_f32_32x32x16_bf16(kf, qf[s], a, 0, 0, 0);
            }
            sa[ct] = a;
        }

        // row max (max3 tree) across 32 scores + lane pair
        float mx = -1e30f;
#pragma unroll
        for (int ct = 0; ct < 2; ++ct) {
            float a = MAX3(sa[ct][0],  sa[ct][1],  sa[ct][2]);
            float b = MAX3(sa[ct][3],  sa[ct][4],  sa[ct][5]);
            float c = MAX3(sa[ct][6],  sa[ct][7],  sa[ct][8]);
            float d = MAX3(sa[ct][9],  sa[ct][10], sa[ct][11]);
            float e = MAX3(sa[ct][12], sa[ct][13], sa[ct][14]);
            float f = MAX3(a, b, sa[ct][15]);
            float g = MAX3(c, d, e);
            mx = MAX3(mx, f, g);
        }
        mx = fmaxf(mx, __shfl_xor(mx, 32));
        mx *= C2;

        float mn = m_i;
        if (!__all(mx - m_i <= THR)) {     // T13 defer-max
            mn = fmaxf(m_i, mx);
            float al = exp2f(m_i - mn);
            l_i *= al;
#pragma unroll
            for (int i = 0; i < 16; ++i) { acc0[i] *= al; acc1[i] *= al; }
            m_i = mn;
        }

        // p = exp2(s*C2 - mn); RNE-pack; l from fp32 p
        float rs = 0.f;
        u32 w[2][8], sw[2][8];
#pragma unroll
        for (int ct = 0; ct < 2; ++ct)
#pragma unroll
            for (int k = 0; k < 8; ++k) {
                float p0 = exp2f(fmaf(sa[ct][2*k],   C2, -mn));
                float p1 = exp2f(fmaf(sa[ct][2*k+1], C2, -mn));
                w[ct][k] = cvtpk(p0, p1);
                rs += p0 + p1;
            }
        rs += __shfl_xor(rs, 32);
        l_i += rs;
#pragma unroll
        for (int ct = 0; ct < 2; ++ct)
#pragma unroll
            for (int k = 0; k < 8; ++k) sw[ct][k] = (u32)__shfl_xor((int)w[ct][k], 32);

        // O^T += V^T * P^T
#pragma unroll
        for (int ct = 0; ct < 2; ++ct)
#pragma unroll
            for (int hf = 0; hf < 2; ++hf) {
                u32 f0 = hi ? sw[ct][4*hf+2] : w[ct][4*hf+0];
                u32 f1 = hi ? sw[ct][4*hf+3] : w[ct][4*hf+1];
                u32 f2 = hi ? w[ct][4*hf+2]  : sw[ct][4*hf+0];
                u32 f3 = hi ? w[ct][4*hf+3]  : sw[ct][4*hf+1];
                int4 pw = make_int4((int)f0, (int)f1, (int)f2, (int)f3);
                bf16x8 pb = __builtin_bit_cast(bf16x8, pw);
#pragma unroll
                for (int dt = 0; dt < 2; ++dt) {
                    int off = (dt*32 + r)*68 + ct*32 + hf*16 + hi*8;
                    short4 v0 = *(const short4*)&Vt_lds[cur][off];
                    short4 v1 = *(const short4*)&Vt_lds[cur][off + 4];
                    bf16x8 av = {v0.x, v0.y, v0.z, v0.w, v1.x, v1.y, v1.z, v1.w};
                    if (dt == 0) acc0 = __builtin_amdgcn_mfma_f32_32x32x16_bf16(av, pb, acc0, 0, 0, 0);
                    else         acc1 = __builtin_amdgcn_mfma_f32_32x32x16_bf16(av, pb, acc1, 0, 0, 0);
                }
            }

        if (t + 1 < SEQ/64) {          // store next tile into other buffer
            const int nxt = cur ^ 1;
#pragma unroll
            for (int i = 0; i < 4; ++i)
                *(bf16x8*)&K_lds[nxt][krow[i]*64 + kps[i]*8] = kreg[i];
#pragma unroll
            for (int j = 0; j < 3; ++j)
#pragma unroll
                for (int e = 0; e < 8; ++e)
                    Vt_lds[nxt][(vd0 + j*8 + e)*68 + vrow] = vreg[j][e];
        }
    }

    float inv = 1.0f / l_i;
#pragma unroll
    for (int g = 0; g < 16; ++g) {
        int d = (g&3) + 8*(g>>2) + 4*hi;
        Ctx[base + (size_t)(q0 + r)*DIM + d] = f2bf(acc0[g] * inv);
    }
#pragma unroll
    for (int g = 0; g < 8; ++g) {
        int d = 32 + (g&3) + 8*(g>>2) + 4*hi;
        Ctx[base + (size_t)(q0 + r)*DIM + d] = f2bf(acc1[g] * inv);
    }
}

extern "C" void kernel_launch(void* const* d_in, const int* in_sizes, int n_in,
                              void* d_out, int out_size, void* d_ws, size_t ws_size,
                              hipStream_t stream)
{
    const float* x  = (const float*)d_in[0];
    const float* Wq = (const float*)d_in[1];
    const float* Wk = (const float*)d_in[2];
    const float* Wv = (const float*)d_in[3];
    const float* Wo = (const float*)d_in[4];
    float* out = (float*)d_out;

    const size_t XN = (size_t)NROWS * DIM;

    short* qb   = (short*)d_ws;
    short* kbuf = qb   + XN;
    short* vbuf = kbuf + XN;
    short* ctxb = vbuf + XN;                 // 25.2 MB total

    dim3 g1(DIM/96, NROWS/128, 3);           // 768 blocks (3.00/CU)
    gemm96<true, false><<<g1, 256, 0, stream>>>(x, Wq, Wk, Wv, qb, kbuf, vbuf);

    dim3 g2(SEQ/64, NH, NB);                 // 1024 blocks (4.00/CU)
    flash3<<<g2, 128, 0, stream>>>(qb, kbuf, vbuf, ctxb);

    dim3 g3(DIM/96, NROWS/128, 1);           // 256 blocks (1.00/CU)
    gemm96<false, true><<<g3, 256, 0, stream>>>(ctxb, Wo, Wo, Wo, out, out, out);
}

// Round 9
// 194.295 us; speedup vs baseline: 1.0456x; 1.0456x over previous
//
#include <hip/hip_runtime.h>
#include <cstdint>

#define DIM 768
#define SEQ 2048
#define NB 2
#define NH 16
#define HD 48
#define NROWS (NB*SEQ)   // 4096
#define QSTR 2304        // fused qkv row stride (Q|K|V column slices)

typedef __attribute__((ext_vector_type(8))) short bf16x8;
typedef __attribute__((ext_vector_type(4))) float f32x4;
typedef __attribute__((ext_vector_type(16))) float f32x16;
typedef unsigned int u32;

__device__ __forceinline__ short f2bf(float f) {
    union { float f; uint32_t u; } v; v.f = f;
    uint32_t u = v.u;
    uint32_t r = (u + 0x7FFFu + ((u >> 16) & 1u)) >> 16;
    return (short)r;
}
__device__ __forceinline__ u32 cvtpk(float lo, float hi) {
    u32 r;
    asm("v_cvt_pk_bf16_f32 %0, %1, %2" : "=v"(r) : "v"(lo), "v"(hi));
    return r;
}

// async global->LDS, 16B per lane; LDS dest = wave-uniform base + lane*16
__device__ __forceinline__ void gload16(const short* g, short* l) {
    __builtin_amdgcn_global_load_lds(
        (const __attribute__((address_space(1))) void*)g,
        (__attribute__((address_space(3))) void*)l, 16, 0, 0);
}

// ---------------------------------------------------------------------------
// fp32 -> bf16 pre-convert: dst = xb | Wq | Wk | Wv | Wo  (R5-verified).
// The middle three form the contiguous [2304][768] fused-QKV B matrix.
// ---------------------------------------------------------------------------
__global__ __launch_bounds__(256)
void cvt_bf16(const float* __restrict__ x,  const float* __restrict__ wq,
              const float* __restrict__ wk, const float* __restrict__ wv,
              const float* __restrict__ wo, short* __restrict__ dst)
{
    const int XN4 = (NROWS*DIM)/4;
    const int WN4 = (DIM*DIM)/4;
    const int T4  = XN4 + 4*WN4;
    for (int i = blockIdx.x*blockDim.x + threadIdx.x; i < T4; i += gridDim.x*blockDim.x) {
        const float* src; int off;
        if (i < XN4) { src = x; off = i; }
        else {
            int j = i - XN4;
            int w = j / WN4, r = j - w*WN4;
            src = (w==0) ? wq : (w==1) ? wk : (w==2) ? wv : wo;
            off = r;
        }
        float4 v = *(const float4*)(src + (size_t)off*4);
        short4 s; s.x=f2bf(v.x); s.y=f2bf(v.y); s.z=f2bf(v.z); s.w=f2bf(v.w);
        *(short4*)(dst + (size_t)i*4) = s;
    }
}

// ---------------------------------------------------------------------------
// bf16 MFMA GEMM, m97-structure: global_load_lds staging, linear LDS,
// 2 barriers per K-step. C = A * B^T. A [M][768], B [N][768] bf16.
// Tile 128(M) x 96(N), BK=64, 256 thr = 4 waves as 2x2 (wave = 64x48).
// Per wave per K-step: 4 A-chunks + 3 B-chunks of global_load_lds dwordx4
// (each = 8 rows x 64 elems, LDS dest wave-uniform base + lane*16).
// CN = C row stride (2304 fused-qkv bf16 / 768 fp32 out).
// ---------------------------------------------------------------------------
template<bool OUT_F32>
__global__ __launch_bounds__(256)
void gemm_gl(const short* __restrict__ A, const short* __restrict__ B,
             void* __restrict__ Cv, int CN)
{
    __shared__ short As[128*64];
    __shared__ short Bs[96*64];

    const int tid  = threadIdx.x;
    const int lane = tid & 63;
    const int wid  = tid >> 6;
    const int wr = wid >> 1, wc = wid & 1;
    const int m  = lane & 15, kb = lane >> 4;
    const int m0 = blockIdx.y * 128, n0 = blockIdx.x * 96;
    const int lr = lane >> 3, lsl = lane & 7;   // row/slot within an 8-row chunk

    f32x4 acc[4][3];
#pragma unroll
    for (int i = 0; i < 4; ++i)
#pragma unroll
        for (int j = 0; j < 3; ++j) acc[i][j] = (f32x4){0.f,0.f,0.f,0.f};

    for (int kt = 0; kt < DIM/64; ++kt) {
        const int k0 = kt * 64;
        __syncthreads();                     // prior iter's frag reads done
#pragma unroll
        for (int i = 0; i < 4; ++i) {        // A rows wid*32 .. +31
            int r0 = wid*32 + i*8;
            gload16(&A[(size_t)(m0 + r0 + lr)*DIM + k0 + lsl*8], &As[r0*64]);
        }
#pragma unroll
        for (int i = 0; i < 3; ++i) {        // B rows wid*24 .. +23
            int r0 = wid*24 + i*8;
            gload16(&B[(size_t)(n0 + r0 + lr)*DIM + k0 + lsl*8], &Bs[r0*64]);
        }
        __syncthreads();                     // vmcnt drained -> tile ready

        bf16x8 af[2][4], bfr[2][3];
#pragma unroll
        for (int t = 0; t < 2; ++t) {
            int sl = (t*4 + kb) * 8;
#pragma unroll
            for (int f = 0; f < 4; ++f)
                af[t][f]  = *(const bf16x8*)&As[(wr*64 + f*16 + m)*64 + sl];
#pragma unroll
            for (int f = 0; f < 3; ++f)
                bfr[t][f] = *(const bf16x8*)&Bs[(wc*48 + f*16 + m)*64 + sl];
        }
#pragma unroll
        for (int fm = 0; fm < 4; ++fm)
#pragma unroll
            for (int fn = 0; fn < 3; ++fn) {
                acc[fm][fn] = __builtin_amdgcn_mfma_f32_16x16x32_bf16(af[0][fm], bfr[0][fn], acc[fm][fn], 0, 0, 0);
                acc[fm][fn] = __builtin_amdgcn_mfma_f32_16x16x32_bf16(af[1][fm], bfr[1][fn], acc[fm][fn], 0, 0, 0);
            }
    }

    // D layout: row = kb*4+r within 16-block, col = m (R5-verified)
#pragma unroll
    for (int fm = 0; fm < 4; ++fm)
#pragma unroll
        for (int fn = 0; fn < 3; ++fn) {
            int col = n0 + wc*48 + fn*16 + m;
#pragma unroll
            for (int r = 0; r < 4; ++r) {
                int row = m0 + wr*64 + fm*16 + kb*4 + r;
                if (OUT_F32)
                    ((float*)Cv)[(size_t)row*CN + col] = acc[fm][fn][r];
                else
                    ((short*)Cv)[(size_t)row*CN + col] = f2bf(acc[fm][fn][r]);
            }
        }
}

// ---------------------------------------------------------------------------
// Flash attention v2 — EXACT R7-verified structure (79.3 us), only change:
// q/k/v are column slices of the fused [4096][2304] qkv buffer (stride QSTR).
// All over-read bytes (K logical slots 6,7) land inside gemm-written qkv.
// ---------------------------------------------------------------------------
__global__ __launch_bounds__(256)
void flash2(const short* __restrict__ Qb, const short* __restrict__ Kb,
            const short* __restrict__ Vb, short* __restrict__ Ctx)
{
    __shared__ short K_lds[64*64];
    __shared__ short Vt_lds[64*68];

    const int tid  = threadIdx.x;
    const int wid  = tid >> 6, lane = tid & 63;
    const int r    = lane & 31, hi = lane >> 5;
    const size_t base  = (size_t)blockIdx.z*SEQ*QSTR + (size_t)blockIdx.y*HD;  // qkv stride
    const size_t baseC = (size_t)blockIdx.z*SEQ*DIM  + (size_t)blockIdx.y*HD;  // ctx stride
    const int q0 = blockIdx.x*128 + wid*32;
    const float C2  = 0.20823688f;   // 48^-0.5 * log2(e)
    const float THR = 11.5f;         // defer-max threshold (~8 nats)

    for (int i = tid; i < 16*68; i += 256) Vt_lds[48*68 + i] = 0;

    bf16x8 qf[3];
#pragma unroll
    for (int s = 0; s < 3; ++s)
        qf[s] = *(const bf16x8*)&Qb[base + (size_t)(q0 + r)*QSTR + s*16 + hi*8];

    f32x16 z16;
#pragma unroll
    for (int i = 0; i < 16; ++i) z16[i] = 0.f;

    f32x16 acc0 = z16, acc1 = z16;
    float m_i = -1e30f, l_i = 0.f;

    const int row0 = tid >> 3,       ps0 = tid & 7;
    const int row1 = (tid+256) >> 3, ps1 = tid & 7;
    const int ls0 = ps0 ^ (row0 & 7), ls1 = ps1 ^ (row1 & 7);

    bf16x8 k0r, k1r; short vreg[12];
    k0r = *(const bf16x8*)&Kb[base + (size_t)row0*QSTR + ls0*8];
    k1r = *(const bf16x8*)&Kb[base + (size_t)row1*QSTR + ls1*8];
#pragma unroll
    for (int j = 0; j < 12; ++j)
        vreg[j] = Vb[base + (size_t)lane*QSTR + wid*12 + j];

    for (int t = 0; t < SEQ/64; ++t) {
        __syncthreads();
        *(bf16x8*)&K_lds[row0*64 + ps0*8] = k0r;
        *(bf16x8*)&K_lds[row1*64 + ps1*8] = k1r;
#pragma unroll
        for (int j = 0; j < 12; ++j)
            Vt_lds[(wid*12 + j)*68 + lane] = vreg[j];
        __syncthreads();

        if (t + 1 < SEQ/64) {
            int c0 = (t+1)*64;
            k0r = *(const bf16x8*)&Kb[base + (size_t)(c0 + row0)*QSTR + ls0*8];
            k1r = *(const bf16x8*)&Kb[base + (size_t)(c0 + row1)*QSTR + ls1*8];
#pragma unroll
            for (int j = 0; j < 12; ++j)
                vreg[j] = Vb[base + (size_t)(c0 + lane)*QSTR + wid*12 + j];
        }

        f32x16 sa[2];
#pragma unroll
        for (int ct = 0; ct < 2; ++ct) {
            f32x16 a = z16;
#pragma unroll
            for (int s = 0; s < 3; ++s) {
                int row = ct*32 + r;
                bf16x8 kf = *(const bf16x8*)&K_lds[row*64 + ((s*2+hi) ^ (row&7))*8];
                a = __builtin_amdgcn_mfma_f32_32x32x16_bf16(kf, qf[s], a, 0, 0, 0);
            }
            sa[ct] = a;
        }

        float mx = -1e30f;
#pragma unroll
        for (int ct = 0; ct < 2; ++ct)
#pragma unroll
            for (int i = 0; i < 16; ++i) mx = fmaxf(mx, sa[ct][i]);
        mx = fmaxf(mx, __shfl_xor(mx, 32));
        mx *= C2;

        float mn = m_i;
        if (!__all(mx - m_i <= THR)) {
            mn = fmaxf(m_i, mx);
            float al = exp2f(m_i - mn);
            l_i *= al;
#pragma unroll
            for (int i = 0; i < 16; ++i) { acc0[i] *= al; acc1[i] *= al; }
            m_i = mn;
        }

        float rs = 0.f;
        u32 w[2][8], sw[2][8];
#pragma unroll
        for (int ct = 0; ct < 2; ++ct)
#pragma unroll
            for (int k = 0; k < 8; ++k) {
                float p0 = exp2f(fmaf(sa[ct][2*k],   C2, -mn));
                float p1 = exp2f(fmaf(sa[ct][2*k+1], C2, -mn));
                w[ct][k] = cvtpk(p0, p1);
                rs += p0 + p1;
            }
        rs += __shfl_xor(rs, 32);
        l_i += rs;
#pragma unroll
        for (int ct = 0; ct < 2; ++ct)
#pragma unroll
            for (int k = 0; k < 8; ++k) sw[ct][k] = (u32)__shfl_xor((int)w[ct][k], 32);

#pragma unroll
        for (int ct = 0; ct < 2; ++ct)
#pragma unroll
            for (int hf = 0; hf < 2; ++hf) {
                u32 f0 = hi ? sw[ct][4*hf+2] : w[ct][4*hf+0];
                u32 f1 = hi ? sw[ct][4*hf+3] : w[ct][4*hf+1];
                u32 f2 = hi ? w[ct][4*hf+2]  : sw[ct][4*hf+0];
                u32 f3 = hi ? w[ct][4*hf+3]  : sw[ct][4*hf+1];
                int4 pw = make_int4((int)f0, (int)f1, (int)f2, (int)f3);
                bf16x8 pb = __builtin_bit_cast(bf16x8, pw);
#pragma unroll
                for (int dt = 0; dt < 2; ++dt) {
                    int off = (dt*32 + r)*68 + ct*32 + hf*16 + hi*8;
                    short4 v0 = *(const short4*)&Vt_lds[off];
                    short4 v1 = *(const short4*)&Vt_lds[off + 4];
                    bf16x8 av = {v0.x, v0.y, v0.z, v0.w, v1.x, v1.y, v1.z, v1.w};
                    if (dt == 0) acc0 = __builtin_amdgcn_mfma_f32_32x32x16_bf16(av, pb, acc0, 0, 0, 0);
                    else         acc1 = __builtin_amdgcn_mfma_f32_32x32x16_bf16(av, pb, acc1, 0, 0, 0);
                }
            }
    }

    float inv = 1.0f / l_i;
#pragma unroll
    for (int g = 0; g < 16; ++g) {
        int d = (g&3) + 8*(g>>2) + 4*hi;
        Ctx[baseC + (size_t)(q0 + r)*DIM + d] = f2bf(acc0[g] * inv);
    }
#pragma unroll
    for (int g = 0; g < 8; ++g) {
        int d = 32 + (g&3) + 8*(g>>2) + 4*hi;
        Ctx[baseC + (size_t)(q0 + r)*DIM + d] = f2bf(acc1[g] * inv);
    }
}

extern "C" void kernel_launch(void* const* d_in, const int* in_sizes, int n_in,
                              void* d_out, int out_size, void* d_ws, size_t ws_size,
                              hipStream_t stream)
{
    const float* x  = (const float*)d_in[0];
    const float* Wq = (const float*)d_in[1];
    const float* Wk = (const float*)d_in[2];
    const float* Wv = (const float*)d_in[3];
    const float* Wo = (const float*)d_in[4];
    float* out = (float*)d_out;

    const size_t XN = (size_t)NROWS * DIM;   // 3,145,728
    const size_t WN = (size_t)DIM * DIM;     //   589,824

    short* xb   = (short*)d_ws;
    short* wcat = xb   + XN;                 // [2304][768] = Wq|Wk|Wv
    short* wob  = wcat + 3*WN;
    short* qkv  = wob  + WN;                 // [4096][2304] bf16
    short* ctxb = qkv  + (size_t)NROWS*QSTR; // [4096][768]  bf16  (~36 MB total)

    cvt_bf16<<<1024, 256, 0, stream>>>(x, Wq, Wk, Wv, Wo, xb);

    dim3 g1(QSTR/96, NROWS/128, 1);          // 24 x 32 = 768 blocks (3.00/CU)
    gemm_gl<false><<<g1, 256, 0, stream>>>(xb, wcat, qkv, QSTR);

    dim3 g2(SEQ/128, NH, NB);                // 512 blocks
    flash2<<<g2, 256, 0, stream>>>(qkv, qkv + DIM, qkv + 2*DIM, ctxb);

    dim3 g3(DIM/96, NROWS/128, 1);           // 8 x 32 = 256 blocks (1.00/CU)
    gemm_gl<true><<<g3, 256, 0, stream>>>(ctxb, wob, out, DIM);
}

// Round 10
// 181.249 us; speedup vs baseline: 1.1209x; 1.0720x over previous
//
#include <hip/hip_runtime.h>
#include <cstdint>

#define DIM 768
#define SEQ 2048
#define NB 2
#define NH 16
#define HD 48
#define NROWS (NB*SEQ)   // 4096

typedef __attribute__((ext_vector_type(8))) short bf16x8;
typedef __attribute__((ext_vector_type(4))) float f32x4;
typedef __attribute__((ext_vector_type(16))) float f32x16;
typedef unsigned int u32;

__device__ __forceinline__ short f2bf(float f) {
    union { float f; uint32_t u; } v; v.f = f;
    uint32_t u = v.u;
    uint32_t r = (u + 0x7FFFu + ((u >> 16) & 1u)) >> 16;
    return (short)r;
}
__device__ __forceinline__ u32 cvtpk(float lo, float hi) {
    u32 r;
    asm("v_cvt_pk_bf16_f32 %0, %1, %2" : "=v"(r) : "v"(lo), "v"(hi));
    return r;
}

// async global->LDS, 16B per lane; LDS dest = wave-uniform base + lane*16
__device__ __forceinline__ void gload16(const short* g, short* l) {
    __builtin_amdgcn_global_load_lds(
        (const __attribute__((address_space(1))) void*)g,
        (__attribute__((address_space(3))) void*)l, 16, 0, 0);
}

// ---------------------------------------------------------------------------
// fp32 -> bf16 pre-convert: dst = xb | Wq | Wk | Wv | Wo (R5-verified).
// Wq|Wk|Wv contiguous = fused [2304][768] QKV B matrix.
// ---------------------------------------------------------------------------
__global__ __launch_bounds__(256)
void cvt_bf16(const float* __restrict__ x,  const float* __restrict__ wq,
              const float* __restrict__ wk, const float* __restrict__ wv,
              const float* __restrict__ wo, short* __restrict__ dst)
{
    const int XN4 = (NROWS*DIM)/4;
    const int WN4 = (DIM*DIM)/4;
    const int T4  = XN4 + 4*WN4;
    for (int i = blockIdx.x*blockDim.x + threadIdx.x; i < T4; i += gridDim.x*blockDim.x) {
        const float* src; int off;
        if (i < XN4) { src = x; off = i; }
        else {
            int j = i - XN4;
            int w = j / WN4, r = j - w*WN4;
            src = (w==0) ? wq : (w==1) ? wk : (w==2) ? wv : wo;
            off = r;
        }
        float4 v = *(const float4*)(src + (size_t)off*4);
        short4 s; s.x=f2bf(v.x); s.y=f2bf(v.y); s.z=f2bf(v.z); s.w=f2bf(v.w);
        *(short4*)(dst + (size_t)i*4) = s;
    }
}

// ---------------------------------------------------------------------------
// bf16 MFMA GEMM: global_load_lds staging + BOTH-sides XOR swizzle (G21):
// global source k-offset pre-swizzled (lsl^lr), LDS linear, frag read uses
// ((t*4+kb)^(m&7)) -> phys slot holds logical slot s^(row&7); read banks
// spread 2 lanes/bank (free, m136). C = A * B^T, tile 128x96, BK=64,
// 4 waves (2x2, wave=64x48). B may be the fused [2304][768] wcat; each
// block's n0 selects output slice C[n0/768] at column n0%768.
// ---------------------------------------------------------------------------
template<bool OUT_F32>
__global__ __launch_bounds__(256)
void gemm_gl(const short* __restrict__ A, const short* __restrict__ B,
             void* __restrict__ C0v, void* __restrict__ C1v, void* __restrict__ C2v)
{
    __shared__ short As[128*64];
    __shared__ short Bs[96*64];

    const int tid  = threadIdx.x;
    const int lane = tid & 63;
    const int wid  = tid >> 6;
    const int wr = wid >> 1, wc = wid & 1;
    const int m  = lane & 15, kb = lane >> 4;
    const int m0 = blockIdx.y * 128, n0 = blockIdx.x * 96;
    const int lr = lane >> 3, lsl = lane & 7;   // row/slot within an 8-row chunk
    const int gsl = (lsl ^ lr) * 8;             // pre-swizzled source k-offset

    void* Cv = C0v;
    const int slice = n0 / DIM;
    if (slice == 1) Cv = C1v; else if (slice == 2) Cv = C2v;
    const int ncol0 = n0 - slice * DIM;

    f32x4 acc[4][3];
#pragma unroll
    for (int i = 0; i < 4; ++i)
#pragma unroll
        for (int j = 0; j < 3; ++j) acc[i][j] = (f32x4){0.f,0.f,0.f,0.f};

    for (int kt = 0; kt < DIM/64; ++kt) {
        const int k0 = kt * 64;
        __syncthreads();                     // prior iter's frag reads done
#pragma unroll
        for (int i = 0; i < 4; ++i) {        // A rows wid*32 .. +31
            int r0 = wid*32 + i*8;
            gload16(&A[(size_t)(m0 + r0 + lr)*DIM + k0 + gsl], &As[r0*64]);
        }
#pragma unroll
        for (int i = 0; i < 3; ++i) {        // B rows wid*24 .. +23
            int r0 = wid*24 + i*8;
            gload16(&B[(size_t)(n0 + r0 + lr)*DIM + k0 + gsl], &Bs[r0*64]);
        }
        __syncthreads();                     // vmcnt drained -> tile ready

        bf16x8 af[2][4], bfr[2][3];
#pragma unroll
        for (int t = 0; t < 2; ++t) {
            int sl = ((t*4 + kb) ^ (m & 7)) * 8;   // logical->phys slot
#pragma unroll
            for (int f = 0; f < 4; ++f)
                af[t][f]  = *(const bf16x8*)&As[(wr*64 + f*16 + m)*64 + sl];
#pragma unroll
            for (int f = 0; f < 3; ++f)
                bfr[t][f] = *(const bf16x8*)&Bs[(wc*48 + f*16 + m)*64 + sl];
        }
#pragma unroll
        for (int fm = 0; fm < 4; ++fm)
#pragma unroll
            for (int fn = 0; fn < 3; ++fn) {
                acc[fm][fn] = __builtin_amdgcn_mfma_f32_16x16x32_bf16(af[0][fm], bfr[0][fn], acc[fm][fn], 0, 0, 0);
                acc[fm][fn] = __builtin_amdgcn_mfma_f32_16x16x32_bf16(af[1][fm], bfr[1][fn], acc[fm][fn], 0, 0, 0);
            }
    }

    // D layout: row = kb*4+r within 16-block, col = m (R5-verified)
#pragma unroll
    for (int fm = 0; fm < 4; ++fm)
#pragma unroll
        for (int fn = 0; fn < 3; ++fn) {
            int col = ncol0 + wc*48 + fn*16 + m;
#pragma unroll
            for (int r = 0; r < 4; ++r) {
                int row = m0 + wr*64 + fm*16 + kb*4 + r;
                if (OUT_F32)
                    ((float*)Cv)[(size_t)row*DIM + col] = acc[fm][fn][r];
                else
                    ((short*)Cv)[(size_t)row*DIM + col] = f2bf(acc[fm][fn][r]);
            }
        }
}

// ---------------------------------------------------------------------------
// Flash attention v2 — EXACT R7-verified kernel (79.3 us): dedicated
// contiguous q/k/v buffers, stride DIM.
// ---------------------------------------------------------------------------
__global__ __launch_bounds__(256)
void flash2(const short* __restrict__ Qb, const short* __restrict__ Kb,
            const short* __restrict__ Vb, short* __restrict__ Ctx)
{
    __shared__ short K_lds[64*64];
    __shared__ short Vt_lds[64*68];

    const int tid  = threadIdx.x;
    const int wid  = tid >> 6, lane = tid & 63;
    const int r    = lane & 31, hi = lane >> 5;
    const size_t base = (size_t)blockIdx.z*SEQ*DIM + (size_t)blockIdx.y*HD;
    const int q0 = blockIdx.x*128 + wid*32;
    const float C2  = 0.20823688f;   // 48^-0.5 * log2(e)
    const float THR = 11.5f;         // defer-max threshold (~8 nats)

    for (int i = tid; i < 16*68; i += 256) Vt_lds[48*68 + i] = 0;

    bf16x8 qf[3];
#pragma unroll
    for (int s = 0; s < 3; ++s)
        qf[s] = *(const bf16x8*)&Qb[base + (size_t)(q0 + r)*DIM + s*16 + hi*8];

    f32x16 z16;
#pragma unroll
    for (int i = 0; i < 16; ++i) z16[i] = 0.f;

    f32x16 acc0 = z16, acc1 = z16;
    float m_i = -1e30f, l_i = 0.f;

    const int row0 = tid >> 3,       ps0 = tid & 7;
    const int row1 = (tid+256) >> 3, ps1 = tid & 7;
    const int ls0 = ps0 ^ (row0 & 7), ls1 = ps1 ^ (row1 & 7);

    bf16x8 k0r, k1r; short vreg[12];
    k0r = *(const bf16x8*)&Kb[base + (size_t)row0*DIM + ls0*8];
    k1r = *(const bf16x8*)&Kb[base + (size_t)row1*DIM + ls1*8];
#pragma unroll
    for (int j = 0; j < 12; ++j)
        vreg[j] = Vb[base + (size_t)lane*DIM + wid*12 + j];

    for (int t = 0; t < SEQ/64; ++t) {
        __syncthreads();
        *(bf16x8*)&K_lds[row0*64 + ps0*8] = k0r;
        *(bf16x8*)&K_lds[row1*64 + ps1*8] = k1r;
#pragma unroll
        for (int j = 0; j < 12; ++j)
            Vt_lds[(wid*12 + j)*68 + lane] = vreg[j];
        __syncthreads();

        if (t + 1 < SEQ/64) {
            int c0 = (t+1)*64;
            k0r = *(const bf16x8*)&Kb[base + (size_t)(c0 + row0)*DIM + ls0*8];
            k1r = *(const bf16x8*)&Kb[base + (size_t)(c0 + row1)*DIM + ls1*8];
#pragma unroll
            for (int j = 0; j < 12; ++j)
                vreg[j] = Vb[base + (size_t)(c0 + lane)*DIM + wid*12 + j];
        }

        f32x16 sa[2];
#pragma unroll
        for (int ct = 0; ct < 2; ++ct) {
            f32x16 a = z16;
#pragma unroll
            for (int s = 0; s < 3; ++s) {
                int row = ct*32 + r;
                bf16x8 kf = *(const bf16x8*)&K_lds[row*64 + ((s*2+hi) ^ (row&7))*8];
                a = __builtin_amdgcn_mfma_f32_32x32x16_bf16(kf, qf[s], a, 0, 0, 0);
            }
            sa[ct] = a;
        }

        float mx = -1e30f;
#pragma unroll
        for (int ct = 0; ct < 2; ++ct)
#pragma unroll
            for (int i = 0; i < 16; ++i) mx = fmaxf(mx, sa[ct][i]);
        mx = fmaxf(mx, __shfl_xor(mx, 32));
        mx *= C2;

        float mn = m_i;
        if (!__all(mx - m_i <= THR)) {
            mn = fmaxf(m_i, mx);
            float al = exp2f(m_i - mn);
            l_i *= al;
#pragma unroll
            for (int i = 0; i < 16; ++i) { acc0[i] *= al; acc1[i] *= al; }
            m_i = mn;
        }

        float rs = 0.f;
        u32 w[2][8], sw[2][8];
#pragma unroll
        for (int ct = 0; ct < 2; ++ct)
#pragma unroll
            for (int k = 0; k < 8; ++k) {
                float p0 = exp2f(fmaf(sa[ct][2*k],   C2, -mn));
                float p1 = exp2f(fmaf(sa[ct][2*k+1], C2, -mn));
                w[ct][k] = cvtpk(p0, p1);
                rs += p0 + p1;
            }
        rs += __shfl_xor(rs, 32);
        l_i += rs;
#pragma unroll
        for (int ct = 0; ct < 2; ++ct)
#pragma unroll
            for (int k = 0; k < 8; ++k) sw[ct][k] = (u32)__shfl_xor((int)w[ct][k], 32);

#pragma unroll
        for (int ct = 0; ct < 2; ++ct)
#pragma unroll
            for (int hf = 0; hf < 2; ++hf) {
                u32 f0 = hi ? sw[ct][4*hf+2] : w[ct][4*hf+0];
                u32 f1 = hi ? sw[ct][4*hf+3] : w[ct][4*hf+1];
                u32 f2 = hi ? w[ct][4*hf+2]  : sw[ct][4*hf+0];
                u32 f3 = hi ? w[ct][4*hf+3]  : sw[ct][4*hf+1];
                int4 pw = make_int4((int)f0, (int)f1, (int)f2, (int)f3);
                bf16x8 pb = __builtin_bit_cast(bf16x8, pw);
#pragma unroll
                for (int dt = 0; dt < 2; ++dt) {
                    int off = (dt*32 + r)*68 + ct*32 + hf*16 + hi*8;
                    short4 v0 = *(const short4*)&Vt_lds[off];
                    short4 v1 = *(const short4*)&Vt_lds[off + 4];
                    bf16x8 av = {v0.x, v0.y, v0.z, v0.w, v1.x, v1.y, v1.z, v1.w};
                    if (dt == 0) acc0 = __builtin_amdgcn_mfma_f32_32x32x16_bf16(av, pb, acc0, 0, 0, 0);
                    else         acc1 = __builtin_amdgcn_mfma_f32_32x32x16_bf16(av, pb, acc1, 0, 0, 0);
                }
            }
    }

    float inv = 1.0f / l_i;
#pragma unroll
    for (int g = 0; g < 16; ++g) {
        int d = (g&3) + 8*(g>>2) + 4*hi;
        Ctx[base + (size_t)(q0 + r)*DIM + d] = f2bf(acc0[g] * inv);
    }
#pragma unroll
    for (int g = 0; g < 8; ++g) {
        int d = 32 + (g&3) + 8*(g>>2) + 4*hi;
        Ctx[base + (size_t)(q0 + r)*DIM + d] = f2bf(acc1[g] * inv);
    }
}

extern "C" void kernel_launch(void* const* d_in, const int* in_sizes, int n_in,
                              void* d_out, int out_size, void* d_ws, size_t ws_size,
                              hipStream_t stream)
{
    const float* x  = (const float*)d_in[0];
    const float* Wq = (const float*)d_in[1];
    const float* Wk = (const float*)d_in[2];
    const float* Wv = (const float*)d_in[3];
    const float* Wo = (const float*)d_in[4];
    float* out = (float*)d_out;

    const size_t XN = (size_t)NROWS * DIM;
    const size_t WN = (size_t)DIM * DIM;

    short* xb   = (short*)d_ws;
    short* wcat = xb   + XN;                 // [2304][768] = Wq|Wk|Wv
    short* wob  = wcat + 3*WN;
    short* qb   = wob  + WN;
    short* kbuf = qb   + XN;
    short* vbuf = kbuf + XN;
    short* ctxb = vbuf + XN;                 // ~29 MB total

    cvt_bf16<<<1024, 256, 0, stream>>>(x, Wq, Wk, Wv, Wo, xb);

    dim3 g1(3*DIM/96, NROWS/128, 1);         // 24 x 32 = 768 blocks (3.00/CU)
    gemm_gl<false><<<g1, 256, 0, stream>>>(xb, wcat, qb, kbuf, vbuf);

    dim3 g2(SEQ/128, NH, NB);                // 512 blocks
    flash2<<<g2, 256, 0, stream>>>(qb, kbuf, vbuf, ctxb);

    dim3 g3(DIM/96, NROWS/128, 1);           // 8 x 32 = 256 blocks (1.00/CU)
    gemm_gl<true><<<g3, 256, 0, stream>>>(ctxb, wob, out, out, out);
}